// Round 6
// baseline (211.903 us; speedup 1.0000x reference)
//
#include <hip/hip_runtime.h>
#include <math.h>

#define BB 8
#define SS 1024
#define DD 768
#define HH 12
#define DHH 64
#define BSS (BB*SS)          // 8192
#define NQKV 2304            // stacked Q|K|V output columns
#define NT 24                // 768 / BK(=32) K-tiles

typedef _Float16 half8 __attribute__((ext_vector_type(8)));
typedef _Float16 half4 __attribute__((ext_vector_type(4)));
typedef float    f32x4 __attribute__((ext_vector_type(4)));

// Async global->LDS DMA, 16 B/lane. LDS dest = wave-uniform base + lane*16.
__device__ __forceinline__ void glds16(const _Float16* g, _Float16* l)
{
    __builtin_amdgcn_global_load_lds(
        (const __attribute__((address_space(1))) uint32_t*)(g),
        (__attribute__((address_space(3))) uint32_t*)(l),
        16, 0, 0);
}

// ---------------------------------------------------------------------------
// prep (unchanged)
// ---------------------------------------------------------------------------
__global__ __launch_bounds__(256)
void prep(const float* __restrict__ x, _Float16* __restrict__ xh,
          const float* __restrict__ Wq, const float* __restrict__ Wk,
          const float* __restrict__ Wv, const float* __restrict__ Wo,
          _Float16* __restrict__ Wt, _Float16* __restrict__ Wot)
{
    const int blk = blockIdx.x;
    const int tid = threadIdx.x;

    if (blk < 3072) {                    // ---- cast x -> f16 ----
        int i = blk * 256 + tid;
        const float4* xp = (const float4*)x + (size_t)i * 2;
        float4 u = xp[0], v = xp[1];
        half8 h = { (_Float16)u.x, (_Float16)u.y, (_Float16)u.z, (_Float16)u.w,
                    (_Float16)v.x, (_Float16)v.y, (_Float16)v.z, (_Float16)v.w };
        ((half8*)xh)[i] = h;
        return;
    }

    // ---- weight transpose: 576 tiles = (12 d0) x (12 n) x (4 z) ----
    __shared__ float T[64][65];
    const int t  = blk - 3072;
    const int z  = t / 144;              // 0..3
    const int r_ = t - z * 144;
    const int d0 = (r_ / 12) * 64;
    const int n_outer = r_ % 12;

    const float* src;
    _Float16* dst;
    int base_mul, row_stride;
    if (z < 3) {
        src = (z == 0) ? Wq : (z == 1) ? Wk : Wv;
        dst = Wt + (size_t)z * DD * DD;
        base_mul = DD * DHH; row_stride = DHH;
    } else {
        src = Wo; dst = Wot;
        base_mul = 64; row_stride = DD;
    }

    const size_t base = (size_t)n_outer * base_mul;
    {
        int dl = tid >> 2, c0 = (tid & 3) * 16;
        const float* p = src + base + (size_t)(d0 + dl) * row_stride + c0;
#pragma unroll
        for (int m = 0; m < 4; ++m) {
            float4 f = *(const float4*)(p + m * 4);
            T[dl][c0 + m*4 + 0] = f.x;
            T[dl][c0 + m*4 + 1] = f.y;
            T[dl][c0 + m*4 + 2] = f.z;
            T[dl][c0 + m*4 + 3] = f.w;
        }
    }
    __syncthreads();
    {
        int e = tid >> 2, c = tid & 3;
        half8 lo, hi;
#pragma unroll
        for (int i = 0; i < 8; ++i) {
            lo[i] = (_Float16)T[c*16 + i][e];
            hi[i] = (_Float16)T[c*16 + 8 + i][e];
        }
        _Float16* q = dst + ((size_t)n_outer * 64 + e) * DD + d0 + c * 16;
        *(half8*)q = lo;
        *(half8*)(q + 8) = hi;
    }
}

// ---------------------------------------------------------------------------
// Stacked QKV GEMM, round-14: round-0's kernel VERBATIM (128x128 tile, BK=32,
// 256 thr, 32 KB LDS -> 4-5 blocks/CU co-resident: cross-block phase overlap
// pipelines LDS reads against MFMA, the m97 mechanism) with ONE change: the
// T2 XOR slot-swizzle (source-side on the DMA, read-side on frags) that
// removes round-0's 16-way ds_read_b128 bank conflict (3.54M conflict
// cycles -> ~0).  Grid 1152, XCD swizzle.  Epilogue unchanged.
// ---------------------------------------------------------------------------
__global__ __launch_bounds__(256)
void gemm_qkv_stacked(const _Float16* __restrict__ Xh, const _Float16* __restrict__ Wt,
                      const float* __restrict__ bq, const float* __restrict__ bk,
                      const float* __restrict__ bv,
                      _Float16* __restrict__ qo, _Float16* __restrict__ ko,
                      _Float16* __restrict__ vto)
{
    __shared__ _Float16 Ash[2][128][32];
    __shared__ _Float16 Bsh[2][128][32];

    const int b = blockIdx.x;            // 0..1151, XCD swizzle
    const int c  = b & 7;
    const int g  = b >> 3;
    const int n_t = g % 18;
    const int m_t = (g / 18) * 8 + c;
    const int m0 = m_t * 128;
    const int n0 = n_t * 128;

    const int tid  = threadIdx.x;
    const int wave = tid >> 6;
    const int lane = tid & 63;
    const int l16  = tid & 15;
    const int quad = (tid >> 4) & 3;
    const int wy = wave >> 1;
    const int wx = wave & 1;

    // T2 swizzle: inverse involution on the global source col (DMA writes
    // linearly -> data lands at swizzled slots); frag reads use same XOR.
    const int scol = ((lane & 3) ^ ((lane >> 3) & 3)) * 8;
    const int fcol = (quad ^ ((l16 >> 1) & 3)) * 8;

    const _Float16* ap = Xh + (size_t)(m0 + 32 * wave + (lane >> 2)) * DD + scol;
    const _Float16* bp = Wt + (size_t)(n0 + 32 * wave + (lane >> 2)) * DD + scol;

    f32x4 acc[4][4];
#pragma unroll
    for (int i = 0; i < 4; ++i)
#pragma unroll
        for (int j = 0; j < 4; ++j) acc[i][j] = (f32x4){0.f, 0.f, 0.f, 0.f};

    glds16(ap, &Ash[0][32 * wave][0]);
    glds16(ap + 16 * DD, &Ash[0][32 * wave + 16][0]);
    glds16(bp, &Bsh[0][32 * wave][0]);
    glds16(bp + 16 * DD, &Bsh[0][32 * wave + 16][0]);

    int cur = 0;
    for (int k0 = 0; k0 < DD; k0 += 32) {
        __syncthreads();                 // buf[cur] DMA done; buf[cur^1] reads done
        if (k0 + 32 < DD) {
            glds16(ap + k0 + 32, &Ash[cur ^ 1][32 * wave][0]);
            glds16(ap + k0 + 32 + 16 * DD, &Ash[cur ^ 1][32 * wave + 16][0]);
            glds16(bp + k0 + 32, &Bsh[cur ^ 1][32 * wave][0]);
            glds16(bp + k0 + 32 + 16 * DD, &Bsh[cur ^ 1][32 * wave + 16][0]);
        }

        half8 a[4], bf[4];
#pragma unroll
        for (int i = 0; i < 4; ++i)
            a[i] = *(const half8*)&Ash[cur][wy * 64 + i * 16 + l16][fcol];
#pragma unroll
        for (int j = 0; j < 4; ++j)
            bf[j] = *(const half8*)&Bsh[cur][wx * 64 + j * 16 + l16][fcol];
#pragma unroll
        for (int i = 0; i < 4; ++i)
#pragma unroll
            for (int j = 0; j < 4; ++j)
                acc[i][j] = __builtin_amdgcn_mfma_f32_16x16x32_f16(a[i], bf[j], acc[i][j], 0, 0, 0);
        cur ^= 1;
    }

    // ---- epilogue ----
    const int w = n0 / 768;              // 0=Q, 1=K, 2=V
    const float* bp_ = (w == 0) ? bq : (w == 1) ? bk : bv;
    const int nb = n0 - w * 768 + wx * 64;
    const float qscale = (w == 0) ? 0.125f : 1.0f;

#pragma unroll
    for (int i = 0; i < 4; ++i) {
#pragma unroll
        for (int r = 0; r < 4; ++r) {
            int row = m0 + wy * 64 + i * 16 + quad * 4 + r;
            int b_ = row >> 10;
            int s  = row & (SS - 1);
#pragma unroll
            for (int j = 0; j < 4; ++j) {
                int nl = nb + j * 16 + l16;          // h*64 + e
                int h = nl >> 6, e = nl & 63;
                float val = (acc[i][j][r] + bp_[nl]) * qscale;
                if (w == 0)
                    qo[((size_t)(b_ * HH + h) * SS + s) * DHH + e] = (_Float16)val;
                else if (w == 1)
                    ko[((size_t)(b_ * HH + h) * SS + s) * DHH + e] = (_Float16)val;
                else
                    vto[((size_t)(b_ * HH + h) * DHH + e) * SS + s] = (_Float16)val;
            }
        }
    }
}

// ---------------------------------------------------------------------------
// Out-projection GEMM (round-1 version, unchanged): 128x64 tile, DMA +
// single-barrier dbuf, wave-tile 64x32, T2 swizzle.
// ---------------------------------------------------------------------------
__global__ __launch_bounds__(256)
void gemm_out_f16(const _Float16* __restrict__ Ah, const _Float16* __restrict__ Bt,
                  const float* __restrict__ bias, float* __restrict__ out)
{
    __shared__ _Float16 Ash[2][128][32];
    __shared__ _Float16 Bsh[2][64][32];

    const int m0 = blockIdx.x * 128;
    const int n0 = blockIdx.y * 64;
    const int tid  = threadIdx.x;
    const int wave = tid >> 6;
    const int lane = tid & 63;
    const int l16  = tid & 15;
    const int quad = (tid >> 4) & 3;
    const int wy = wave >> 1;
    const int wx = wave & 1;

    const int scol = ((lane & 3) ^ ((lane >> 3) & 3)) * 8;
    const int fcol = (quad ^ ((l16 >> 1) & 3)) * 8;

    const _Float16* ap = Ah + (size_t)(m0 + 32 * wave + (lane >> 2)) * DD + scol;
    const _Float16* bp = Bt + (size_t)(n0 + 16 * wave + (lane >> 2)) * DD + scol;

    f32x4 acc[4][2];
#pragma unroll
    for (int i = 0; i < 4; ++i)
#pragma unroll
        for (int j = 0; j < 2; ++j) acc[i][j] = (f32x4){0.f, 0.f, 0.f, 0.f};

    glds16(ap, &Ash[0][32 * wave][0]);
    glds16(ap + 16 * DD, &Ash[0][32 * wave + 16][0]);
    glds16(bp, &Bsh[0][16 * wave][0]);

    int cur = 0;
    for (int k0 = 0; k0 < DD; k0 += 32) {
        __syncthreads();
        if (k0 + 32 < DD) {
            glds16(ap + k0 + 32, &Ash[cur ^ 1][32 * wave][0]);
            glds16(ap + k0 + 32 + 16 * DD, &Ash[cur ^ 1][32 * wave + 16][0]);
            glds16(bp + k0 + 32, &Bsh[cur ^ 1][16 * wave][0]);
        }

        half8 a[4], bf[2];
#pragma unroll
        for (int i = 0; i < 4; ++i)
            a[i] = *(const half8*)&Ash[cur][wy * 64 + i * 16 + l16][fcol];
#pragma unroll
        for (int j = 0; j < 2; ++j)
            bf[j] = *(const half8*)&Bsh[cur][wx * 32 + j * 16 + l16][fcol];
#pragma unroll
        for (int i = 0; i < 4; ++i)
#pragma unroll
            for (int j = 0; j < 2; ++j)
                acc[i][j] = __builtin_amdgcn_mfma_f32_16x16x32_f16(a[i], bf[j], acc[i][j], 0, 0, 0);
        cur ^= 1;
    }

#pragma unroll
    for (int i = 0; i < 4; ++i) {
#pragma unroll
        for (int r = 0; r < 4; ++r) {
            int row = m0 + wy * 64 + i * 16 + quad * 4 + r;
#pragma unroll
            for (int j = 0; j < 2; ++j) {
                int col = n0 + wx * 32 + j * 16 + l16;
                out[(size_t)row * DD + col] = acc[i][j][r] + bias[col];
            }
        }
    }
}

// ---------------------------------------------------------------------------
// Flash attention, round-14 change: V-frag LDS reads HOISTED before the
// exp/Pt round-trip (independent of P; previously they serialized after the
// Pt read's lgkmcnt drain).  V reads now complete under the 16 __expf's.
// Everything else identical to round 1.  50 KB LDS -> 3 blocks/CU.
// ---------------------------------------------------------------------------
__global__ __launch_bounds__(512)
void attn_f16(const _Float16* __restrict__ qh, const _Float16* __restrict__ kh,
              const _Float16* __restrict__ vt, _Float16* __restrict__ ctxh)
{
    const int bh  = blockIdx.x;
    const int q0  = blockIdx.y * 128;
    const int tid = threadIdx.x;
    const int wave = tid >> 6;          // 0..7
    const int lane = tid & 63;
    const int l16  = tid & 15;
    const int quad = (tid >> 4) & 3;

    __shared__ _Float16 Ks[2][2][64][32];   // [dbuf][d-chunk][key][32]
    __shared__ _Float16 Vt[2][2][64][32];   // [dbuf][kk-chunk][e][32]
    __shared__ _Float16 Pt[8][16][72];      // per-wave P [q][kk]

    const int scol = ((lane & 3) ^ ((lane >> 3) & 3)) * 8;
    const int fcol = (quad ^ ((l16 >> 1) & 3)) * 8;

    // ---- Q frags: direct global (once) ----
    const _Float16* qrow = qh + ((size_t)bh * SS + q0 + wave * 16 + l16) * DHH;
    const half8 qlo = *(const half8*)(qrow + quad * 8);
    const half8 qhi = *(const half8*)(qrow + 32 + quad * 8);

    // ---- DMA sources: sub-wave sw covers 16 rows of its matrix ----
    const int sw = wave & 3;
    const _Float16* kp = kh + ((size_t)bh * SS + 16 * sw + (lane >> 2)) * DHH + scol;
    const _Float16* vp = vt + ((size_t)bh * DHH + 16 * sw + (lane >> 2)) * SS + scol;

    f32x4 o[4];
    float lacc = 0.f;
#pragma unroll
    for (int j = 0; j < 4; ++j) o[j] = (f32x4){0.f, 0.f, 0.f, 0.f};

    // ---- prefetch tile 0 -> buffer 0 ----
    if (wave < 4) {
        glds16(kp,      &Ks[0][0][16 * sw][0]);
        glds16(kp + 32, &Ks[0][1][16 * sw][0]);
    } else {
        glds16(vp,      &Vt[0][0][16 * sw][0]);
        glds16(vp + 32, &Vt[0][1][16 * sw][0]);
    }

    int cur = 0;
    for (int kt = 0; kt < SS; kt += 64) {
        __syncthreads();                 // buf[cur] ready; buf[cur^1] reads done
        if (kt + 64 < SS) {
            if (wave < 4) {
                glds16(kp + (size_t)(kt + 64) * DHH,      &Ks[cur ^ 1][0][16 * sw][0]);
                glds16(kp + (size_t)(kt + 64) * DHH + 32, &Ks[cur ^ 1][1][16 * sw][0]);
            } else {
                glds16(vp + kt + 64,      &Vt[cur ^ 1][0][16 * sw][0]);
                glds16(vp + kt + 64 + 32, &Vt[cur ^ 1][1][16 * sw][0]);
            }
        }

        // ---- QK^T for all 4 kk-subtiles ----
        f32x4 z[4];
#pragma unroll
        for (int f = 0; f < 4; ++f) {
            half8 klo = *(const half8*)&Ks[cur][0][f * 16 + l16][fcol];
            half8 khi = *(const half8*)&Ks[cur][1][f * 16 + l16][fcol];
            z[f] = (f32x4){0.f, 0.f, 0.f, 0.f};
            z[f] = __builtin_amdgcn_mfma_f32_16x16x32_f16(klo, qlo, z[f], 0, 0, 0);
            z[f] = __builtin_amdgcn_mfma_f32_16x16x32_f16(khi, qhi, z[f], 0, 0, 0);
        }

        // ---- V-frag prefetch (independent of P; completes under exp) ----
        half8 vv0[4], vv1[4];
#pragma unroll
        for (int j = 0; j < 4; ++j) {
            vv0[j] = *(const half8*)&Vt[cur][0][j * 16 + l16][fcol];
            vv1[j] = *(const half8*)&Vt[cur][1][j * 16 + l16][fcol];
        }

        // ---- exp; vectorized P write ----
#pragma unroll
        for (int f = 0; f < 4; ++f) {
            half4 pk;
#pragma unroll
            for (int r = 0; r < 4; ++r) {
                float p = __expf(z[f][r]);
                lacc += p;
                pk[r] = (_Float16)p;
            }
            *(half4*)&Pt[wave][l16][f * 16 + quad * 4] = pk;
        }

        // ---- P A-frags (same-wave LDS round trip, in-order DS) ----
        half8 pl = *(const half8*)&Pt[wave][l16][quad * 8];
        half8 ph = *(const half8*)&Pt[wave][l16][32 + quad * 8];

        // ---- PV ----
#pragma unroll
        for (int j = 0; j < 4; ++j) {
            o[j] = __builtin_amdgcn_mfma_f32_16x16x32_f16(pl, vv0[j], o[j], 0, 0, 0);
            o[j] = __builtin_amdgcn_mfma_f32_16x16x32_f16(ph, vv1[j], o[j], 0, 0, 0);
        }
        cur ^= 1;
    }

    // ---- l: sum quad partials (same q = l16 across quads) ----
    float lr = lacc;
    lr += __shfl_xor(lr, 16);
    lr += __shfl_xor(lr, 32);

    const int b_ = bh / HH;
    const int h_ = bh % HH;
#pragma unroll
    for (int r = 0; r < 4; ++r) {
        float invl = 1.f / __shfl(lr, quad * 4 + r, 16);
        int s_ = q0 + wave * 16 + quad * 4 + r;
        _Float16* orow = ctxh + ((size_t)(b_ * SS + s_)) * DD + h_ * DHH;
#pragma unroll
        for (int j = 0; j < 4; ++j)
            orow[j * 16 + l16] = (_Float16)(o[j][r] * invl);
    }
}

// ---------------------------------------------------------------------------
extern "C" void kernel_launch(void* const* d_in, const int* in_sizes, int n_in,
                              void* d_out, int out_size, void* d_ws, size_t ws_size,
                              hipStream_t stream)
{
    const float* x  = (const float*)d_in[0];
    const float* Wq = (const float*)d_in[1];
    const float* bq = (const float*)d_in[2];
    const float* Wk = (const float*)d_in[3];
    const float* bk = (const float*)d_in[4];
    const float* Wv = (const float*)d_in[5];
    const float* bv = (const float*)d_in[6];
    const float* Wo = (const float*)d_in[7];
    const float* bo = (const float*)d_in[8];
    float* out = (float*)d_out;

    const size_t xe = (size_t)BSS * DD;          // 6,291,456
    const size_t we = (size_t)DD * DD;           // 589,824
    _Float16* Xh   = (_Float16*)d_ws;
    _Float16* Wt   = Xh  + xe;                   // [2304][768]
    _Float16* Wot  = Wt  + (size_t)3 * we;
    _Float16* qhb  = Wot + we;
    _Float16* khb  = qhb + xe;
    _Float16* vtb  = khb + xe;                   // [bh][e][s]
    _Float16* ctxh = vtb + xe;

    prep<<<3072 + 576, 256, 0, stream>>>(x, Xh, Wq, Wk, Wv, Wo, Wt, Wot);

    gemm_qkv_stacked<<<(BSS / 128) * (NQKV / 128), 256, 0, stream>>>(
        Xh, Wt, bq, bk, bv, qhb, khb, vtb);

    dim3 ag(BB * HH, SS / 128);      // (96, 8) = 768 blocks
    attn_f16<<<ag, 512, 0, stream>>>(qhb, khb, vtb, ctxh);

    dim3 gg(BSS / 128, DD / 64);     // (64, 12) = 768 blocks
    gemm_out_f16<<<gg, 256, 0, stream>>>(ctxh, Wot, bo, out);
}

// Round 7
// 211.119 us; speedup vs baseline: 1.0037x; 1.0037x over previous
//
#include <hip/hip_runtime.h>
#include <math.h>

#define BB 8
#define SS 1024
#define DD 768
#define HH 12
#define DHH 64
#define BSS (BB*SS)          // 8192
#define NQKV 2304            // stacked Q|K|V output columns
#define NT 24                // 768 / 32 (legacy kernels)
#define NT64 12              // 768 / 64 (8-phase kernel)

typedef _Float16 half8 __attribute__((ext_vector_type(8)));
typedef _Float16 half4 __attribute__((ext_vector_type(4)));
typedef float    f32x4 __attribute__((ext_vector_type(4)));

// Async global->LDS DMA, 16 B/lane. LDS dest = wave-uniform base + lane*16.
__device__ __forceinline__ void glds16(const _Float16* g, _Float16* l)
{
    __builtin_amdgcn_global_load_lds(
        (const __attribute__((address_space(1))) uint32_t*)(g),
        (__attribute__((address_space(3))) uint32_t*)(l),
        16, 0, 0);
}

#define WAITV(N) asm volatile("s_waitcnt vmcnt(" #N ")" ::: "memory")
#define MF(a, b, c) __builtin_amdgcn_mfma_f32_16x16x32_f16(a, b, c, 0, 0, 0)

// ---------------------------------------------------------------------------
// prep (unchanged)
// ---------------------------------------------------------------------------
__global__ __launch_bounds__(256)
void prep(const float* __restrict__ x, _Float16* __restrict__ xh,
          const float* __restrict__ Wq, const float* __restrict__ Wk,
          const float* __restrict__ Wv, const float* __restrict__ Wo,
          _Float16* __restrict__ Wt, _Float16* __restrict__ Wot)
{
    const int blk = blockIdx.x;
    const int tid = threadIdx.x;

    if (blk < 3072) {                    // ---- cast x -> f16 ----
        int i = blk * 256 + tid;
        const float4* xp = (const float4*)x + (size_t)i * 2;
        float4 u = xp[0], v = xp[1];
        half8 h = { (_Float16)u.x, (_Float16)u.y, (_Float16)u.z, (_Float16)u.w,
                    (_Float16)v.x, (_Float16)v.y, (_Float16)v.z, (_Float16)v.w };
        ((half8*)xh)[i] = h;
        return;
    }

    // ---- weight transpose: 576 tiles = (12 d0) x (12 n) x (4 z) ----
    __shared__ float T[64][65];
    const int t  = blk - 3072;
    const int z  = t / 144;              // 0..3
    const int r_ = t - z * 144;
    const int d0 = (r_ / 12) * 64;
    const int n_outer = r_ % 12;

    const float* src;
    _Float16* dst;
    int base_mul, row_stride;
    if (z < 3) {
        src = (z == 0) ? Wq : (z == 1) ? Wk : Wv;
        dst = Wt + (size_t)z * DD * DD;
        base_mul = DD * DHH; row_stride = DHH;
    } else {
        src = Wo; dst = Wot;
        base_mul = 64; row_stride = DD;
    }

    const size_t base = (size_t)n_outer * base_mul;
    {
        int dl = tid >> 2, c0 = (tid & 3) * 16;
        const float* p = src + base + (size_t)(d0 + dl) * row_stride + c0;
#pragma unroll
        for (int m = 0; m < 4; ++m) {
            float4 f = *(const float4*)(p + m * 4);
            T[dl][c0 + m*4 + 0] = f.x;
            T[dl][c0 + m*4 + 1] = f.y;
            T[dl][c0 + m*4 + 2] = f.z;
            T[dl][c0 + m*4 + 3] = f.w;
        }
    }
    __syncthreads();
    {
        int e = tid >> 2, c = tid & 3;
        half8 lo, hi;
#pragma unroll
        for (int i = 0; i < 8; ++i) {
            lo[i] = (_Float16)T[c*16 + i][e];
            hi[i] = (_Float16)T[c*16 + 8 + i][e];
        }
        _Float16* q = dst + ((size_t)n_outer * 64 + e) * DD + d0 + c * 16;
        *(half8*)q = lo;
        *(half8*)(q + 8) = hi;
    }
}

// ---------------------------------------------------------------------------
// Stacked QKV GEMM, round-15: faithful m201 8-phase port.  256x256 tile,
// BK=64, 512 thr / 8 waves (2Mx4N, wave-tile 128x64, acc[8][4]).  LDS
// 128 KB: [2 dbuf][2 half][128][64] per matrix.  4 phases per K-tile, each
// {ds_read frags | stage -> s_barrier -> lgkmcnt(0)+sched_barrier ->
// setprio(1) -> 16 MFMA -> setprio(0) -> s_barrier}.  Staging of tile t+1
// front-loaded into phases 0 (A) and 1 (B) so the end-of-tile vmcnt(0)
// gate waits on ~2-phase-old L2 hits (cheap).  XOR slot-swizzle (8 slots
// ^ row&7) on DMA source and frag reads.  Grid 32x9 = 288, XCD-swizzled.
// ---------------------------------------------------------------------------
__global__ __launch_bounds__(512, 2)
void gemm_qkv_8ph(const _Float16* __restrict__ Xh, const _Float16* __restrict__ Wt,
                  const float* __restrict__ bq, const float* __restrict__ bk,
                  const float* __restrict__ bv,
                  _Float16* __restrict__ qo, _Float16* __restrict__ ko,
                  _Float16* __restrict__ vto)
{
    __shared__ _Float16 Ab[2][2][128][64];   // 64 KB
    __shared__ _Float16 Bb[2][2][128][64];   // 64 KB

    const int bid = blockIdx.x;          // 0..287
    const int c8  = bid & 7;             // XCD (288 % 8 == 0)
    const int g   = bid >> 3;            // 0..35
    const int m_t = c8 * 4 + g / 9;      // 0..31
    const int n_t = g % 9;               // 0..8
    const int m0 = m_t * 256;
    const int n0 = n_t * 256;

    const int tid  = threadIdx.x;
    const int wave = tid >> 6;           // 0..7
    const int lane = tid & 63;
    const int l16  = tid & 15;
    const int quad = (tid >> 4) & 3;
    const int l7   = l16 & 7;
    const int wy = wave >> 2;            // 0..1 (A half)
    const int wx = wave & 3;             // 0..3 (B quarter)

    // DMA source pre-swizzle: row&7 = lane>>3 for all staged rows.
    const int scol = ((lane & 7) ^ ((lane >> 3) & 7)) * 8;

    // staging: wave covers 32 rows (4 glds x 8 rows) of each matrix.
    const _Float16* apS = Xh + (size_t)(m0 + wave * 32 + (lane >> 3)) * DD + scol;
    const _Float16* bpS = Wt + (size_t)(n0 + wave * 32 + (lane >> 3)) * DD + scol;
    const int sh = wave >> 2;            // dest half
    const int sr = (wave & 3) * 32;      // dest row base within half

#define STAGE_A(nb, t1) do { _Pragma("unroll")                              \
    for (int i_ = 0; i_ < 4; ++i_)                                          \
        glds16(apS + (size_t)i_ * 8 * DD + (t1) * 64,                       \
               &Ab[nb][sh][sr + i_ * 8][0]); } while (0)
#define STAGE_B(nb, t1) do { _Pragma("unroll")                              \
    for (int i_ = 0; i_ < 4; ++i_)                                          \
        glds16(bpS + (size_t)i_ * 8 * DD + (t1) * 64,                       \
               &Bb[nb][sh][sr + i_ * 8][0]); } while (0)

    // frag reads: same involution (slot = ks*4+quad, ^ row&7 = l7)
#define RD_A(buf, m, ks) (*(const half8*)&Ab[buf][wy][(m)*16 + l16][((((ks)*4 + quad)) ^ l7) * 8])
#define RD_B(buf, j, ks) (*(const half8*)&Bb[buf][wx >> 1][(wx & 1)*64 + (j)*16 + l16][((((ks)*4 + quad)) ^ l7) * 8])

    f32x4 acc[8][4];
#pragma unroll
    for (int i = 0; i < 8; ++i)
#pragma unroll
        for (int j = 0; j < 4; ++j) acc[i][j] = (f32x4){0.f, 0.f, 0.f, 0.f};

    // phase body: read A-frags for m = M0,M0+1; optional stage; barrier;
    // lgkmcnt(0)+sched_barrier (rule #18); setprio-wrapped 16 MFMA; barrier.
#define PHASE(buf, M0, STG, GATE)                                           \
    {                                                                       \
        half8 a00 = RD_A(buf, (M0), 0),     a01 = RD_A(buf, (M0), 1);       \
        half8 a10 = RD_A(buf, (M0) + 1, 0), a11 = RD_A(buf, (M0) + 1, 1);   \
        STG;                                                                \
        __builtin_amdgcn_s_barrier();                                       \
        asm volatile("s_waitcnt lgkmcnt(0)" ::: "memory");                  \
        __builtin_amdgcn_sched_barrier(0);                                  \
        __builtin_amdgcn_s_setprio(1);                                      \
        _Pragma("unroll")                                                   \
        for (int j = 0; j < 4; ++j) {                                       \
            acc[(M0)][j]     = MF(a00, bf[j][0], acc[(M0)][j]);             \
            acc[(M0)][j]     = MF(a01, bf[j][1], acc[(M0)][j]);             \
            acc[(M0) + 1][j] = MF(a10, bf[j][0], acc[(M0) + 1][j]);         \
            acc[(M0) + 1][j] = MF(a11, bf[j][1], acc[(M0) + 1][j]);         \
        }                                                                   \
        __builtin_amdgcn_s_setprio(0);                                      \
        GATE;                                                               \
        __builtin_amdgcn_s_barrier();                                       \
    }

    // ---- prologue: stage tile 0, drain, sync ----
    STAGE_A(0, 0); STAGE_B(0, 0);
    WAITV(0);
    __builtin_amdgcn_s_barrier();

#pragma unroll 2
    for (int t = 0; t < NT64; ++t) {
        const int buf = t & 1;
        const int nb  = buf ^ 1;
        const bool stg = (t + 1 < NT64);

        half8 bf[4][2];
#pragma unroll
        for (int j = 0; j < 4; ++j) {
            bf[j][0] = RD_B(buf, j, 0);
            bf[j][1] = RD_B(buf, j, 1);
        }

        PHASE(buf, 0, if (stg) STAGE_A(nb, t + 1), );        // phase 0
        PHASE(buf, 2, if (stg) STAGE_B(nb, t + 1), );        // phase 1
        PHASE(buf, 4, , );                                   // phase 2
        PHASE(buf, 6, , if (stg) WAITV(0));                  // phase 3 + gate
    }

#undef PHASE
#undef RD_A
#undef RD_B
#undef STAGE_A
#undef STAGE_B

    // ---- epilogue: n-tile (256 cols) entirely within Q, K, or V ----
    const int wsel = n0 / 768;           // 0=Q, 1=K, 2=V (768 % 256 == 0)
    const int nb_ = n0 - wsel * 768 + wx * 64;
    const float* bp_ = (wsel == 0) ? bq : (wsel == 1) ? bk : bv;

    float bvv[4]; int hh4[4], ee4[4];
#pragma unroll
    for (int j = 0; j < 4; ++j) {
        int nl = nb_ + j * 16 + l16;     // h*64 + e
        bvv[j] = bp_[nl];
        hh4[j] = nl >> 6;
        ee4[j] = nl & 63;
    }

    if (wsel == 0) {
#pragma unroll
        for (int i = 0; i < 8; ++i)
#pragma unroll
            for (int r = 0; r < 4; ++r) {
                int row = m0 + wy * 128 + i * 16 + quad * 4 + r;
                int b_ = row >> 10;
                int s  = row & (SS - 1);
#pragma unroll
                for (int j = 0; j < 4; ++j) {
                    float val = (acc[i][j][r] + bvv[j]) * 0.125f;
                    qo[((size_t)(b_ * HH + hh4[j]) * SS + s) * DHH + ee4[j]] = (_Float16)val;
                }
            }
    } else if (wsel == 1) {
#pragma unroll
        for (int i = 0; i < 8; ++i)
#pragma unroll
            for (int r = 0; r < 4; ++r) {
                int row = m0 + wy * 128 + i * 16 + quad * 4 + r;
                int b_ = row >> 10;
                int s  = row & (SS - 1);
#pragma unroll
                for (int j = 0; j < 4; ++j) {
                    float val = acc[i][j][r] + bvv[j];
                    ko[((size_t)(b_ * HH + hh4[j]) * SS + s) * DHH + ee4[j]] = (_Float16)val;
                }
            }
    } else {
#pragma unroll
        for (int i = 0; i < 8; ++i)
#pragma unroll
            for (int r = 0; r < 4; ++r) {
                int row = m0 + wy * 128 + i * 16 + quad * 4 + r;
                int b_ = row >> 10;
                int s  = row & (SS - 1);
#pragma unroll
                for (int j = 0; j < 4; ++j) {
                    float val = acc[i][j][r] + bvv[j];
                    vto[((size_t)(b_ * HH + hh4[j]) * DHH + ee4[j]) * SS + s] = (_Float16)val;
                }
            }
    }
}

// ---------------------------------------------------------------------------
// Out-projection GEMM (round-1 version): 128x64 tile, DMA + single-barrier
// dbuf, wave-tile 64x32, T2 swizzle.
// ---------------------------------------------------------------------------
__global__ __launch_bounds__(256)
void gemm_out_f16(const _Float16* __restrict__ Ah, const _Float16* __restrict__ Bt,
                  const float* __restrict__ bias, float* __restrict__ out)
{
    __shared__ _Float16 Ash[2][128][32];
    __shared__ _Float16 Bsh[2][64][32];

    const int m0 = blockIdx.x * 128;
    const int n0 = blockIdx.y * 64;
    const int tid  = threadIdx.x;
    const int wave = tid >> 6;
    const int lane = tid & 63;
    const int l16  = tid & 15;
    const int quad = (tid >> 4) & 3;
    const int wy = wave >> 1;
    const int wx = wave & 1;

    const int scol = ((lane & 3) ^ ((lane >> 3) & 3)) * 8;
    const int fcol = (quad ^ ((l16 >> 1) & 3)) * 8;

    const _Float16* ap = Ah + (size_t)(m0 + 32 * wave + (lane >> 2)) * DD + scol;
    const _Float16* bp = Bt + (size_t)(n0 + 16 * wave + (lane >> 2)) * DD + scol;

    f32x4 acc[4][2];
#pragma unroll
    for (int i = 0; i < 4; ++i)
#pragma unroll
        for (int j = 0; j < 2; ++j) acc[i][j] = (f32x4){0.f, 0.f, 0.f, 0.f};

    glds16(ap, &Ash[0][32 * wave][0]);
    glds16(ap + 16 * DD, &Ash[0][32 * wave + 16][0]);
    glds16(bp, &Bsh[0][16 * wave][0]);

    int cur = 0;
    for (int k0 = 0; k0 < DD; k0 += 32) {
        __syncthreads();
        if (k0 + 32 < DD) {
            glds16(ap + k0 + 32, &Ash[cur ^ 1][32 * wave][0]);
            glds16(ap + k0 + 32 + 16 * DD, &Ash[cur ^ 1][32 * wave + 16][0]);
            glds16(bp + k0 + 32, &Bsh[cur ^ 1][16 * wave][0]);
        }

        half8 a[4], bf[2];
#pragma unroll
        for (int i = 0; i < 4; ++i)
            a[i] = *(const half8*)&Ash[cur][wy * 64 + i * 16 + l16][fcol];
#pragma unroll
        for (int j = 0; j < 2; ++j)
            bf[j] = *(const half8*)&Bsh[cur][wx * 32 + j * 16 + l16][fcol];
#pragma unroll
        for (int i = 0; i < 4; ++i)
#pragma unroll
            for (int j = 0; j < 2; ++j)
                acc[i][j] = MF(a[i], bf[j], acc[i][j]);
        cur ^= 1;
    }

#pragma unroll
    for (int i = 0; i < 4; ++i) {
#pragma unroll
        for (int r = 0; r < 4; ++r) {
            int row = m0 + wy * 64 + i * 16 + quad * 4 + r;
#pragma unroll
            for (int j = 0; j < 2; ++j) {
                int col = n0 + wx * 32 + j * 16 + l16;
                out[(size_t)row * DD + col] = acc[i][j][r] + bias[col];
            }
        }
    }
}

// ---------------------------------------------------------------------------
// Flash attention (round-6 version with V-frag hoist).
// ---------------------------------------------------------------------------
__global__ __launch_bounds__(512)
void attn_f16(const _Float16* __restrict__ qh, const _Float16* __restrict__ kh,
              const _Float16* __restrict__ vt, _Float16* __restrict__ ctxh)
{
    const int bh  = blockIdx.x;
    const int q0  = blockIdx.y * 128;
    const int tid = threadIdx.x;
    const int wave = tid >> 6;          // 0..7
    const int lane = tid & 63;
    const int l16  = tid & 15;
    const int quad = (tid >> 4) & 3;

    __shared__ _Float16 Ks[2][2][64][32];   // [dbuf][d-chunk][key][32]
    __shared__ _Float16 Vt[2][2][64][32];   // [dbuf][kk-chunk][e][32]
    __shared__ _Float16 Pt[8][16][72];      // per-wave P [q][kk]

    const int scol = ((lane & 3) ^ ((lane >> 3) & 3)) * 8;
    const int fcol = (quad ^ ((l16 >> 1) & 3)) * 8;

    // ---- Q frags: direct global (once) ----
    const _Float16* qrow = qh + ((size_t)bh * SS + q0 + wave * 16 + l16) * DHH;
    const half8 qlo = *(const half8*)(qrow + quad * 8);
    const half8 qhi = *(const half8*)(qrow + 32 + quad * 8);

    // ---- DMA sources: sub-wave sw covers 16 rows of its matrix ----
    const int sw = wave & 3;
    const _Float16* kp = kh + ((size_t)bh * SS + 16 * sw + (lane >> 2)) * DHH + scol;
    const _Float16* vp = vt + ((size_t)bh * DHH + 16 * sw + (lane >> 2)) * SS + scol;

    f32x4 o[4];
    float lacc = 0.f;
#pragma unroll
    for (int j = 0; j < 4; ++j) o[j] = (f32x4){0.f, 0.f, 0.f, 0.f};

    // ---- prefetch tile 0 -> buffer 0 ----
    if (wave < 4) {
        glds16(kp,      &Ks[0][0][16 * sw][0]);
        glds16(kp + 32, &Ks[0][1][16 * sw][0]);
    } else {
        glds16(vp,      &Vt[0][0][16 * sw][0]);
        glds16(vp + 32, &Vt[0][1][16 * sw][0]);
    }

    int cur = 0;
    for (int kt = 0; kt < SS; kt += 64) {
        __syncthreads();                 // buf[cur] ready; buf[cur^1] reads done
        if (kt + 64 < SS) {
            if (wave < 4) {
                glds16(kp + (size_t)(kt + 64) * DHH,      &Ks[cur ^ 1][0][16 * sw][0]);
                glds16(kp + (size_t)(kt + 64) * DHH + 32, &Ks[cur ^ 1][1][16 * sw][0]);
            } else {
                glds16(vp + kt + 64,      &Vt[cur ^ 1][0][16 * sw][0]);
                glds16(vp + kt + 64 + 32, &Vt[cur ^ 1][1][16 * sw][0]);
            }
        }

        // ---- QK^T for all 4 kk-subtiles ----
        f32x4 z[4];
#pragma unroll
        for (int f = 0; f < 4; ++f) {
            half8 klo = *(const half8*)&Ks[cur][0][f * 16 + l16][fcol];
            half8 khi = *(const half8*)&Ks[cur][1][f * 16 + l16][fcol];
            z[f] = (f32x4){0.f, 0.f, 0.f, 0.f};
            z[f] = MF(klo, qlo, z[f]);
            z[f] = MF(khi, qhi, z[f]);
        }

        // ---- V-frag prefetch (independent of P; completes under exp) ----
        half8 vv0[4], vv1[4];
#pragma unroll
        for (int j = 0; j < 4; ++j) {
            vv0[j] = *(const half8*)&Vt[cur][0][j * 16 + l16][fcol];
            vv1[j] = *(const half8*)&Vt[cur][1][j * 16 + l16][fcol];
        }

        // ---- exp; vectorized P write ----
#pragma unroll
        for (int f = 0; f < 4; ++f) {
            half4 pk;
#pragma unroll
            for (int r = 0; r < 4; ++r) {
                float p = __expf(z[f][r]);
                lacc += p;
                pk[r] = (_Float16)p;
            }
            *(half4*)&Pt[wave][l16][f * 16 + quad * 4] = pk;
        }

        // ---- P A-frags (same-wave LDS round trip, in-order DS) ----
        half8 pl = *(const half8*)&Pt[wave][l16][quad * 8];
        half8 ph = *(const half8*)&Pt[wave][l16][32 + quad * 8];

        // ---- PV ----
#pragma unroll
        for (int j = 0; j < 4; ++j) {
            o[j] = MF(pl, vv0[j], o[j]);
            o[j] = MF(ph, vv1[j], o[j]);
        }
        cur ^= 1;
    }

    // ---- l: sum quad partials (same q = l16 across quads) ----
    float lr = lacc;
    lr += __shfl_xor(lr, 16);
    lr += __shfl_xor(lr, 32);

    const int b_ = bh / HH;
    const int h_ = bh % HH;
#pragma unroll
    for (int r = 0; r < 4; ++r) {
        float invl = 1.f / __shfl(lr, quad * 4 + r, 16);
        int s_ = q0 + wave * 16 + quad * 4 + r;
        _Float16* orow = ctxh + ((size_t)(b_ * SS + s_)) * DD + h_ * DHH;
#pragma unroll
        for (int j = 0; j < 4; ++j)
            orow[j * 16 + l16] = (_Float16)(o[j][r] * invl);
    }
}

// ---------------------------------------------------------------------------
extern "C" void kernel_launch(void* const* d_in, const int* in_sizes, int n_in,
                              void* d_out, int out_size, void* d_ws, size_t ws_size,
                              hipStream_t stream)
{
    const float* x  = (const float*)d_in[0];
    const float* Wq = (const float*)d_in[1];
    const float* bq = (const float*)d_in[2];
    const float* Wk = (const float*)d_in[3];
    const float* bk = (const float*)d_in[4];
    const float* Wv = (const float*)d_in[5];
    const float* bv = (const float*)d_in[6];
    const float* Wo = (const float*)d_in[7];
    const float* bo = (const float*)d_in[8];
    float* out = (float*)d_out;

    const size_t xe = (size_t)BSS * DD;          // 6,291,456
    const size_t we = (size_t)DD * DD;           // 589,824
    _Float16* Xh   = (_Float16*)d_ws;
    _Float16* Wt   = Xh  + xe;                   // [2304][768]
    _Float16* Wot  = Wt  + (size_t)3 * we;
    _Float16* qhb  = Wot + we;
    _Float16* khb  = qhb + xe;
    _Float16* vtb  = khb + xe;                   // [bh][e][s]
    _Float16* ctxh = vtb + xe;

    prep<<<3072 + 576, 256, 0, stream>>>(x, Xh, Wq, Wk, Wv, Wo, Wt, Wot);

    gemm_qkv_8ph<<<(BSS / 256) * (NQKV / 256), 512, 0, stream>>>(
        Xh, Wt, bq, bk, bv, qhb, khb, vtb);

    dim3 ag(BB * HH, SS / 128);      // (96, 8) = 768 blocks
    attn_f16<<<ag, 512, 0, stream>>>(qhb, khb, vtb, ctxh);

    dim3 gg(BSS / 128, DD / 64);     // (64, 12) = 768 blocks
    gemm_out_f16<<<gg, 256, 0, stream>>>(ctxh, Wot, bo, out);
}

// Round 8
// 205.102 us; speedup vs baseline: 1.0332x; 1.0293x over previous
//
#include <hip/hip_runtime.h>
#include <math.h>

#define BB 8
#define SS 1024
#define DD 768
#define HH 12
#define DHH 64
#define BSS (BB*SS)          // 8192
#define NQKV 2304            // stacked Q|K|V output columns
#define NT 24                // 768 / BK(=32) K-tiles

typedef _Float16 half8 __attribute__((ext_vector_type(8)));
typedef _Float16 half4 __attribute__((ext_vector_type(4)));
typedef float    f32x4 __attribute__((ext_vector_type(4)));

// Async global->LDS DMA, 16 B/lane. LDS dest = wave-uniform base + lane*16.
__device__ __forceinline__ void glds16(const _Float16* g, _Float16* l)
{
    __builtin_amdgcn_global_load_lds(
        (const __attribute__((address_space(1))) uint32_t*)(g),
        (__attribute__((address_space(3))) uint32_t*)(l),
        16, 0, 0);
}

#define MF(a, b, c) __builtin_amdgcn_mfma_f32_16x16x32_f16(a, b, c, 0, 0, 0)

// ---------------------------------------------------------------------------
// prep (unchanged)
// ---------------------------------------------------------------------------
__global__ __launch_bounds__(256)
void prep(const float* __restrict__ x, _Float16* __restrict__ xh,
          const float* __restrict__ Wq, const float* __restrict__ Wk,
          const float* __restrict__ Wv, const float* __restrict__ Wo,
          _Float16* __restrict__ Wt, _Float16* __restrict__ Wot)
{
    const int blk = blockIdx.x;
    const int tid = threadIdx.x;

    if (blk < 3072) {                    // ---- cast x -> f16 ----
        int i = blk * 256 + tid;
        const float4* xp = (const float4*)x + (size_t)i * 2;
        float4 u = xp[0], v = xp[1];
        half8 h = { (_Float16)u.x, (_Float16)u.y, (_Float16)u.z, (_Float16)u.w,
                    (_Float16)v.x, (_Float16)v.y, (_Float16)v.z, (_Float16)v.w };
        ((half8*)xh)[i] = h;
        return;
    }

    // ---- weight transpose: 576 tiles = (12 d0) x (12 n) x (4 z) ----
    __shared__ float T[64][65];
    const int t  = blk - 3072;
    const int z  = t / 144;              // 0..3
    const int r_ = t - z * 144;
    const int d0 = (r_ / 12) * 64;
    const int n_outer = r_ % 12;

    const float* src;
    _Float16* dst;
    int base_mul, row_stride;
    if (z < 3) {
        src = (z == 0) ? Wq : (z == 1) ? Wk : Wv;
        dst = Wt + (size_t)z * DD * DD;
        base_mul = DD * DHH; row_stride = DHH;
    } else {
        src = Wo; dst = Wot;
        base_mul = 64; row_stride = DD;
    }

    const size_t base = (size_t)n_outer * base_mul;
    {
        int dl = tid >> 2, c0 = (tid & 3) * 16;
        const float* p = src + base + (size_t)(d0 + dl) * row_stride + c0;
#pragma unroll
        for (int m = 0; m < 4; ++m) {
            float4 f = *(const float4*)(p + m * 4);
            T[dl][c0 + m*4 + 0] = f.x;
            T[dl][c0 + m*4 + 1] = f.y;
            T[dl][c0 + m*4 + 2] = f.z;
            T[dl][c0 + m*4 + 3] = f.w;
        }
    }
    __syncthreads();
    {
        int e = tid >> 2, c = tid & 3;
        half8 lo, hi;
#pragma unroll
        for (int i = 0; i < 8; ++i) {
            lo[i] = (_Float16)T[c*16 + i][e];
            hi[i] = (_Float16)T[c*16 + 8 + i][e];
        }
        _Float16* q = dst + ((size_t)n_outer * 64 + e) * DD + d0 + c * 16;
        *(half8*)q = lo;
        *(half8*)(q + 8) = hi;
    }
}

// ---------------------------------------------------------------------------
// Stacked QKV GEMM: round-1's kernel VERBATIM (session best, 57.3 us).
// 256x256 tile, BK=32, 8 waves (2Mx4N), quad-buffered LDS, staging 3 tiles
// ahead, ONE counted-vmcnt gate + raw s_barrier per K-tile, setprio, T2
// XOR slot-swizzle, XCD-bijective grid swizzle (288 % 8 == 0).
// ---------------------------------------------------------------------------
__global__ __launch_bounds__(512, 2)
void gemm_qkv_256(const _Float16* __restrict__ Xh, const _Float16* __restrict__ Wt,
                  const float* __restrict__ bq, const float* __restrict__ bk,
                  const float* __restrict__ bv,
                  _Float16* __restrict__ qo, _Float16* __restrict__ ko,
                  _Float16* __restrict__ vto)
{
    __shared__ _Float16 Ab[4][256][32];
    __shared__ _Float16 Bb[4][256][32];

    const int bid = blockIdx.x;          // 0..287
    const int c = bid & 7;               // XCD
    const int g = bid >> 3;              // 0..35
    const int m0 = (c * 4 + g / 9) * 256;
    const int n0 = (g % 9) * 256;

    const int tid  = threadIdx.x;
    const int wave = tid >> 6;           // 0..7
    const int lane = tid & 63;
    const int l16  = tid & 15;
    const int quad = (tid >> 4) & 3;
    const int wy = wave >> 2;            // 0..1 : wave tile 128x64
    const int wx = wave & 3;             // 0..3

    const int scol = ((lane & 3) ^ ((lane >> 3) & 3)) * 8;
    const _Float16* ap0 = Xh + (size_t)(m0 + wave * 32 + (lane >> 2)) * DD + scol;
    const _Float16* bp0 = Wt + (size_t)(n0 + wave * 32 + (lane >> 2)) * DD + scol;

    const int fcol = (quad ^ ((l16 >> 1) & 3)) * 8;

    f32x4 acc[8][4];
#pragma unroll
    for (int i = 0; i < 8; ++i)
#pragma unroll
        for (int j = 0; j < 4; ++j) acc[i][j] = (f32x4){0.f, 0.f, 0.f, 0.f};

    // ---- prologue: stage tiles 0,1,2 (tile-major FIFO: A,A,B,B per tile) ----
#pragma unroll
    for (int t = 0; t < 3; ++t) {
        glds16(ap0 + t * 32,           &Ab[t][wave * 32][0]);
        glds16(ap0 + t * 32 + 16 * DD, &Ab[t][wave * 32 + 16][0]);
        glds16(bp0 + t * 32,           &Bb[t][wave * 32][0]);
        glds16(bp0 + t * 32 + 16 * DD, &Bb[t][wave * 32 + 16][0]);
    }
    asm volatile("s_waitcnt vmcnt(8)\n\ts_barrier" ::: "memory");

#pragma unroll 4
    for (int kt = 0; kt < NT; ++kt) {
        const int bf = kt & 3;

        // ---------- phase A : n-frags 0,1 ----------
        half8 a[8], bA[2];
#pragma unroll
        for (int i = 0; i < 8; ++i)
            a[i] = *(const half8*)&Ab[bf][wy * 128 + i * 16 + l16][fcol];
#pragma unroll
        for (int j = 0; j < 2; ++j)
            bA[j] = *(const half8*)&Bb[bf][wx * 64 + j * 16 + l16][fcol];
        if (kt + 3 < NT) {
            const int nf = (kt + 3) & 3;
            glds16(ap0 + (kt + 3) * 32,           &Ab[nf][wave * 32][0]);
            glds16(ap0 + (kt + 3) * 32 + 16 * DD, &Ab[nf][wave * 32 + 16][0]);
        }
        __builtin_amdgcn_s_setprio(1);
#pragma unroll
        for (int i = 0; i < 8; ++i) {
            acc[i][0] = MF(a[i], bA[0], acc[i][0]);
            acc[i][1] = MF(a[i], bA[1], acc[i][1]);
        }
        __builtin_amdgcn_s_setprio(0);

        // ---------- phase B : n-frags 2,3 ----------
        half8 bB[2];
#pragma unroll
        for (int j = 0; j < 2; ++j)
            bB[j] = *(const half8*)&Bb[bf][wx * 64 + (2 + j) * 16 + l16][fcol];
        if (kt + 3 < NT) {
            const int nf = (kt + 3) & 3;
            glds16(bp0 + (kt + 3) * 32,           &Bb[nf][wave * 32][0]);
            glds16(bp0 + (kt + 3) * 32 + 16 * DD, &Bb[nf][wave * 32 + 16][0]);
        }
        __builtin_amdgcn_s_setprio(1);
#pragma unroll
        for (int i = 0; i < 8; ++i) {
            acc[i][2] = MF(a[i], bB[0], acc[i][2]);
            acc[i][3] = MF(a[i], bB[1], acc[i][3]);
        }
        __builtin_amdgcn_s_setprio(0);

        // ---------- gate: tile kt+1 must be resident before next iter ----------
        if (kt < NT - 3)
            asm volatile("s_waitcnt vmcnt(8)\n\ts_barrier" ::: "memory");
        else if (kt == NT - 3)
            asm volatile("s_waitcnt vmcnt(4)\n\ts_barrier" ::: "memory");
        else if (kt == NT - 2)
            asm volatile("s_waitcnt vmcnt(0)\n\ts_barrier" ::: "memory");
    }

    // ---- epilogue (w selected per block: 768 = 3*256) ----
    const int wsel  = n0 / 768;          // 0=Q, 1=K, 2=V
    const int ncol0 = n0 - wsel * 768 + wx * 64;

    if (wsel == 0) {
#pragma unroll
        for (int i = 0; i < 8; ++i) {
#pragma unroll
            for (int r = 0; r < 4; ++r) {
                int row = m0 + wy * 128 + i * 16 + quad * 4 + r;
                int b_ = row >> 10;
                int s  = row & (SS - 1);
#pragma unroll
                for (int j = 0; j < 4; ++j) {
                    int nl = ncol0 + j * 16 + l16;       // h*64 + e
                    int h = nl >> 6, e = nl & 63;
                    float val = (acc[i][j][r] + bq[nl]) * 0.125f;
                    qo[((size_t)(b_ * HH + h) * SS + s) * DHH + e] = (_Float16)val;
                }
            }
        }
    } else if (wsel == 1) {
#pragma unroll
        for (int i = 0; i < 8; ++i) {
#pragma unroll
            for (int r = 0; r < 4; ++r) {
                int row = m0 + wy * 128 + i * 16 + quad * 4 + r;
                int b_ = row >> 10;
                int s  = row & (SS - 1);
#pragma unroll
                for (int j = 0; j < 4; ++j) {
                    int nl = ncol0 + j * 16 + l16;
                    int h = nl >> 6, e = nl & 63;
                    float val = acc[i][j][r] + bk[nl];
                    ko[((size_t)(b_ * HH + h) * SS + s) * DHH + e] = (_Float16)val;
                }
            }
        }
    } else {
#pragma unroll
        for (int i = 0; i < 8; ++i) {
#pragma unroll
            for (int r = 0; r < 4; ++r) {
                int row = m0 + wy * 128 + i * 16 + quad * 4 + r;
                int b_ = row >> 10;
                int s  = row & (SS - 1);
#pragma unroll
                for (int j = 0; j < 4; ++j) {
                    int nl = ncol0 + j * 16 + l16;
                    int h = nl >> 6, e = nl & 63;
                    float val = acc[i][j][r] + bv[nl];
                    vto[((size_t)(b_ * HH + h) * DHH + e) * SS + s] = (_Float16)val;
                }
            }
        }
    }
}

// ---------------------------------------------------------------------------
// Out-projection GEMM (round-1 version): 128x64 tile, DMA + single-barrier
// dbuf, wave-tile 64x32, T2 swizzle.
// ---------------------------------------------------------------------------
__global__ __launch_bounds__(256)
void gemm_out_f16(const _Float16* __restrict__ Ah, const _Float16* __restrict__ Bt,
                  const float* __restrict__ bias, float* __restrict__ out)
{
    __shared__ _Float16 Ash[2][128][32];
    __shared__ _Float16 Bsh[2][64][32];

    const int m0 = blockIdx.x * 128;
    const int n0 = blockIdx.y * 64;
    const int tid  = threadIdx.x;
    const int wave = tid >> 6;
    const int lane = tid & 63;
    const int l16  = tid & 15;
    const int quad = (tid >> 4) & 3;
    const int wy = wave >> 1;
    const int wx = wave & 1;

    const int scol = ((lane & 3) ^ ((lane >> 3) & 3)) * 8;
    const int fcol = (quad ^ ((l16 >> 1) & 3)) * 8;

    const _Float16* ap = Ah + (size_t)(m0 + 32 * wave + (lane >> 2)) * DD + scol;
    const _Float16* bp = Bt + (size_t)(n0 + 16 * wave + (lane >> 2)) * DD + scol;

    f32x4 acc[4][2];
#pragma unroll
    for (int i = 0; i < 4; ++i)
#pragma unroll
        for (int j = 0; j < 2; ++j) acc[i][j] = (f32x4){0.f, 0.f, 0.f, 0.f};

    glds16(ap, &Ash[0][32 * wave][0]);
    glds16(ap + 16 * DD, &Ash[0][32 * wave + 16][0]);
    glds16(bp, &Bsh[0][16 * wave][0]);

    int cur = 0;
    for (int k0 = 0; k0 < DD; k0 += 32) {
        __syncthreads();
        if (k0 + 32 < DD) {
            glds16(ap + k0 + 32, &Ash[cur ^ 1][32 * wave][0]);
            glds16(ap + k0 + 32 + 16 * DD, &Ash[cur ^ 1][32 * wave + 16][0]);
            glds16(bp + k0 + 32, &Bsh[cur ^ 1][16 * wave][0]);
        }

        half8 a[4], bf[2];
#pragma unroll
        for (int i = 0; i < 4; ++i)
            a[i] = *(const half8*)&Ash[cur][wy * 64 + i * 16 + l16][fcol];
#pragma unroll
        for (int j = 0; j < 2; ++j)
            bf[j] = *(const half8*)&Bsh[cur][wx * 32 + j * 16 + l16][fcol];
#pragma unroll
        for (int i = 0; i < 4; ++i)
#pragma unroll
            for (int j = 0; j < 2; ++j)
                acc[i][j] = MF(a[i], bf[j], acc[i][j]);
        cur ^= 1;
    }

#pragma unroll
    for (int i = 0; i < 4; ++i) {
#pragma unroll
        for (int r = 0; r < 4; ++r) {
            int row = m0 + wy * 64 + i * 16 + quad * 4 + r;
#pragma unroll
            for (int j = 0; j < 2; ++j) {
                int col = n0 + wx * 32 + j * 16 + l16;
                out[(size_t)row * DD + col] = acc[i][j][r] + bias[col];
            }
        }
    }
}

// ---------------------------------------------------------------------------
// Flash attention, round-16 restructure: 4 waves x 32 q-rows (256 thr).
// K/V fragment reads are shared across both 16-q subtiles of a wave ->
// per-CU LDS-pipe traffic per MFMA drops ~1.5-1.7x (the measured-structure
// bottleneck: 8-wave version spent ~35 us of DS-pipe occupancy per CU vs a
// 12.4 us MFMA floor).  Same grid (96 x 8 = 768 blocks = 3/CU), LDS
// 51.2 KB -> 3 blocks/CU.  V-hoist and T2 swizzle kept.
// ---------------------------------------------------------------------------
__global__ __launch_bounds__(256)
void attn_f16(const _Float16* __restrict__ qh, const _Float16* __restrict__ kh,
              const _Float16* __restrict__ vt, _Float16* __restrict__ ctxh)
{
    const int bh  = blockIdx.x;
    const int q0  = blockIdx.y * 128;
    const int tid = threadIdx.x;
    const int wave = tid >> 6;          // 0..3
    const int lane = tid & 63;
    const int l16  = tid & 15;
    const int quad = (tid >> 4) & 3;

    __shared__ _Float16 Ks[2][2][64][32];   // [dbuf][d-chunk][key][32]
    __shared__ _Float16 Vs[2][2][64][32];   // [dbuf][kk-chunk][e][32]
    __shared__ _Float16 Pt[4][32][72];      // per-wave P [q 32][kk 64+pad]

    const int scol = ((lane & 3) ^ ((lane >> 3) & 3)) * 8;
    const int fcol = (quad ^ ((l16 >> 1) & 3)) * 8;

    // ---- Q frags: two 16-row subtiles per wave (rows wave*32 + {0..15,16..31})
    const _Float16* qrow0 = qh + ((size_t)bh * SS + q0 + wave * 32 + l16) * DHH;
    const half8 qlo0 = *(const half8*)(qrow0 + quad * 8);
    const half8 qhi0 = *(const half8*)(qrow0 + 32 + quad * 8);
    const half8 qlo1 = *(const half8*)(qrow0 + 16 * DHH + quad * 8);
    const half8 qhi1 = *(const half8*)(qrow0 + 16 * DHH + 32 + quad * 8);

    // ---- DMA sources: wave w stages K rows [16w,16w+16) + V rows [16w,16w+16)
    const _Float16* kp = kh + ((size_t)bh * SS + 16 * wave + (lane >> 2)) * DHH + scol;
    const _Float16* vp = vt + ((size_t)bh * DHH + 16 * wave + (lane >> 2)) * SS + scol;

    f32x4 o0[4], o1[4];
    float lacc0 = 0.f, lacc1 = 0.f;
#pragma unroll
    for (int j = 0; j < 4; ++j) {
        o0[j] = (f32x4){0.f, 0.f, 0.f, 0.f};
        o1[j] = (f32x4){0.f, 0.f, 0.f, 0.f};
    }

    // ---- prefetch tile 0 -> buffer 0 (4 glds per wave) ----
    glds16(kp,      &Ks[0][0][16 * wave][0]);
    glds16(kp + 32, &Ks[0][1][16 * wave][0]);
    glds16(vp,      &Vs[0][0][16 * wave][0]);
    glds16(vp + 32, &Vs[0][1][16 * wave][0]);

    int cur = 0;
    for (int kt = 0; kt < SS; kt += 64) {
        __syncthreads();                 // buf[cur] ready; buf[cur^1] reads done
        if (kt + 64 < SS) {
            glds16(kp + (size_t)(kt + 64) * DHH,      &Ks[cur ^ 1][0][16 * wave][0]);
            glds16(kp + (size_t)(kt + 64) * DHH + 32, &Ks[cur ^ 1][1][16 * wave][0]);
            glds16(vp + kt + 64,      &Vs[cur ^ 1][0][16 * wave][0]);
            glds16(vp + kt + 64 + 32, &Vs[cur ^ 1][1][16 * wave][0]);
        }

        // ---- QK^T: K-frags read ONCE, used by both q-subtiles ----
        f32x4 z0[4], z1[4];
#pragma unroll
        for (int f = 0; f < 4; ++f) {
            half8 klo = *(const half8*)&Ks[cur][0][f * 16 + l16][fcol];
            half8 khi = *(const half8*)&Ks[cur][1][f * 16 + l16][fcol];
            z0[f] = (f32x4){0.f, 0.f, 0.f, 0.f};
            z0[f] = MF(klo, qlo0, z0[f]);
            z0[f] = MF(khi, qhi0, z0[f]);
            z1[f] = (f32x4){0.f, 0.f, 0.f, 0.f};
            z1[f] = MF(klo, qlo1, z1[f]);
            z1[f] = MF(khi, qhi1, z1[f]);
        }

        // ---- V-frag prefetch (independent of P; completes under exp) ----
        half8 vv0[4], vv1[4];
#pragma unroll
        for (int j = 0; j < 4; ++j) {
            vv0[j] = *(const half8*)&Vs[cur][0][j * 16 + l16][fcol];
            vv1[j] = *(const half8*)&Vs[cur][1][j * 16 + l16][fcol];
        }

        // ---- exp; vectorized P writes for both subtiles ----
#pragma unroll
        for (int f = 0; f < 4; ++f) {
            half4 pk0, pk1;
#pragma unroll
            for (int r = 0; r < 4; ++r) {
                float p0 = __expf(z0[f][r]); lacc0 += p0; pk0[r] = (_Float16)p0;
                float p1 = __expf(z1[f][r]); lacc1 += p1; pk1[r] = (_Float16)p1;
            }
            *(half4*)&Pt[wave][l16][f * 16 + quad * 4]      = pk0;
            *(half4*)&Pt[wave][16 + l16][f * 16 + quad * 4] = pk1;
        }

        // ---- P A-frags (same-wave LDS round trip, in-order DS) ----
        half8 pl0 = *(const half8*)&Pt[wave][l16][quad * 8];
        half8 ph0 = *(const half8*)&Pt[wave][l16][32 + quad * 8];
        half8 pl1 = *(const half8*)&Pt[wave][16 + l16][quad * 8];
        half8 ph1 = *(const half8*)&Pt[wave][16 + l16][32 + quad * 8];

        // ---- PV: V-frags shared across both q-subtiles ----
#pragma unroll
        for (int j = 0; j < 4; ++j) {
            o0[j] = MF(pl0, vv0[j], o0[j]);
            o0[j] = MF(ph0, vv1[j], o0[j]);
            o1[j] = MF(pl1, vv0[j], o1[j]);
            o1[j] = MF(ph1, vv1[j], o1[j]);
        }
        cur ^= 1;
    }

    // ---- l: sum quad partials (same q = l16 across quads) ----
    float lr0 = lacc0;
    lr0 += __shfl_xor(lr0, 16);
    lr0 += __shfl_xor(lr0, 32);
    float lr1 = lacc1;
    lr1 += __shfl_xor(lr1, 16);
    lr1 += __shfl_xor(lr1, 32);

    const int b_ = bh / HH;
    const int h_ = bh % HH;
#pragma unroll
    for (int r = 0; r < 4; ++r) {
        float inv0 = 1.f / __shfl(lr0, quad * 4 + r, 16);
        float inv1 = 1.f / __shfl(lr1, quad * 4 + r, 16);
        int s0_ = q0 + wave * 32 + quad * 4 + r;
        _Float16* orow0 = ctxh + ((size_t)(b_ * SS + s0_)) * DD + h_ * DHH;
        _Float16* orow1 = ctxh + ((size_t)(b_ * SS + s0_ + 16)) * DD + h_ * DHH;
#pragma unroll
        for (int j = 0; j < 4; ++j) {
            orow0[j * 16 + l16] = (_Float16)(o0[j][r] * inv0);
            orow1[j * 16 + l16] = (_Float16)(o1[j][r] * inv1);
        }
    }
}

// ---------------------------------------------------------------------------
extern "C" void kernel_launch(void* const* d_in, const int* in_sizes, int n_in,
                              void* d_out, int out_size, void* d_ws, size_t ws_size,
                              hipStream_t stream)
{
    const float* x  = (const float*)d_in[0];
    const float* Wq = (const float*)d_in[1];
    const float* bq = (const float*)d_in[2];
    const float* Wk = (const float*)d_in[3];
    const float* bk = (const float*)d_in[4];
    const float* Wv = (const float*)d_in[5];
    const float* bv = (const float*)d_in[6];
    const float* Wo = (const float*)d_in[7];
    const float* bo = (const float*)d_in[8];
    float* out = (float*)d_out;

    const size_t xe = (size_t)BSS * DD;          // 6,291,456
    const size_t we = (size_t)DD * DD;           // 589,824
    _Float16* Xh   = (_Float16*)d_ws;
    _Float16* Wt   = Xh  + xe;                   // [2304][768]
    _Float16* Wot  = Wt  + (size_t)3 * we;
    _Float16* qhb  = Wot + we;
    _Float16* khb  = qhb + xe;
    _Float16* vtb  = khb + xe;                   // [bh][e][s]
    _Float16* ctxh = vtb + xe;

    prep<<<3072 + 576, 256, 0, stream>>>(x, Xh, Wq, Wk, Wv, Wo, Wt, Wot);

    gemm_qkv_256<<<(BSS / 256) * (NQKV / 256), 512, 0, stream>>>(
        Xh, Wt, bq, bk, bv, qhb, khb, vtb);

    dim3 ag(BB * HH, SS / 128);      // (96, 8) = 768 blocks
    attn_f16<<<ag, 256, 0, stream>>>(qhb, khb, vtb, ctxh);

    dim3 gg(BSS / 128, DD / 64);     // (64, 12) = 768 blocks
    gemm_out_f16<<<gg, 256, 0, stream>>>(ctxh, Wot, bo, out);
}